// Round 2
// baseline (14435.124 us; speedup 1.0000x reference)
//
#include <hip/hip_runtime.h>
#include <hip/hip_bf16.h>

typedef __attribute__((ext_vector_type(4))) float f32x4;
typedef __attribute__((ext_vector_type(8))) short s16x8;

#define DEVFN static __device__ __forceinline__

// ---- problem sizes ----
#define TT  160
#define BB  640
#define DD  40
#define HH  768
#define PP  256
#define G4H 3072

// ---- geometry ----
// 144 gate blocks: 3 layers x 48 col-slices (16 H-cols = 64 z-cols each), all 640 rows.
// 48 proj blocks: 3 layers x (4 mt x 4 nt), one step behind gates (off critical path).
#define NGATE 144
#define NWG   192
#define NTHR  256      // 4 waves, 10x4 frag per wave (round-1 lesson: keep per-wave ILP)
#define SSTEPS 165     // max region: proj l=2 t=159 -> s = 159+4+1 = 164

#define KX0 64         // layer0 x-K padded 40 -> 64
#define KS  768        // recurrent K: s(t-1) @ Wph  (Wph = Wp @ Wh, fused)

// LDS strides (elements); +8 pad keeps 16B alignment, breaks worst conflicts
#define STW1 840       // layer0: 64+768 + 8
#define STW2 1032      // layer1/2: 256+768 + 8
#define STP  776       // proj: 768+8
#define LDS_ELEMS 66048  // 64*1032 = 132,096 bytes

// ---- workspace layout ----
#define XP_BYTES   (TT*BB*64*2)
#define HR_BYTES   (3*4*BB*PP*2)
#define SB_BYTES   (3*2*BB*HH*2)      // double-buffered now (parity t&1)
#define XP_OFF     0
#define HR_OFF     (XP_OFF + XP_BYTES)
#define SB_OFF     (HR_OFF + HR_BYTES)
#define SYNC_OFF   (SB_OFF + SB_BYTES)
#define SYNC_BYTES 4096

DEVFN float sigm(float v)  { return __fdividef(1.f, 1.f + __expf(-v)); }
DEVFN float tanh_(float v) { return 2.f * __fdividef(1.f, 1.f + __expf(-2.f * v)) - 1.f; }
DEVFN f32x4 f4zero() { f32x4 v; v[0]=0.f; v[1]=0.f; v[2]=0.f; v[3]=0.f; return v; }

// write-through bf16 store: visible at coherence point once vmcnt retires.
DEVFN void gst_b16(__hip_bfloat16* p, __hip_bfloat16 v) {
  unsigned short u = __builtin_bit_cast(unsigned short, v);
  asm volatile("global_store_short %0, %1, off sc0 sc1" :: "v"(p), "v"(u));
}

// two-level monotonic counter barrier; k = 1,2,3,... strictly increasing.
DEVFN void gridbar(unsigned* sync, int bid, unsigned k) {
  __syncthreads();   // drains vmcnt(0): all sc0sc1 stores are at coherence point
  if (threadIdx.x == 0) {
    unsigned* gc = sync + (bid & 7) * 64;             // 8 group counters, 256B apart
    unsigned a = __hip_atomic_fetch_add(gc, 1u, __ATOMIC_RELAXED, __HIP_MEMORY_SCOPE_AGENT);
    if (a == k * (NWG / 8) - 1) {                     // last of my 24-block group
      unsigned* rc = sync + 8 * 64;
      unsigned r = __hip_atomic_fetch_add(rc, 1u, __ATOMIC_RELAXED, __HIP_MEMORY_SCOPE_AGENT);
      if (r == k * 8 - 1) {
        __hip_atomic_store(sync + 9 * 64, k, __ATOMIC_RELAXED, __HIP_MEMORY_SCOPE_AGENT);
      }
    }
    while (__hip_atomic_load(sync + 9 * 64, __ATOMIC_RELAXED, __HIP_MEMORY_SCOPE_AGENT) < k) {
      __builtin_amdgcn_s_sleep(1);
    }
    __builtin_amdgcn_fence(__ATOMIC_ACQUIRE, "agent");  // buffer_inv: kill stale lines
  }
  __syncthreads();
}

__global__ __launch_bounds__(NTHR, 1)
void lstmp_persistent(const float* __restrict__ xin,
                      const float* __restrict__ W0, const float* __restrict__ b0, const float* __restrict__ Wp0,
                      const float* __restrict__ W1, const float* __restrict__ b1, const float* __restrict__ Wp1,
                      const float* __restrict__ W2, const float* __restrict__ b2, const float* __restrict__ Wp2,
                      float* __restrict__ outp, unsigned char* __restrict__ ws)
{
  __shared__ __align__(16) __hip_bfloat16 lds[LDS_ELEMS];

  const int bid  = blockIdx.x;
  const int tid  = threadIdx.x;
  const int lane = tid & 63;
  const int wave = tid >> 6;      // 0..3
  const int q    = lane >> 4;     // 0..3
  const int c16  = lane & 15;

  __hip_bfloat16* Xp = (__hip_bfloat16*)(ws + XP_OFF);  // [160][640][64] bf16, cols>=40 zero
  __hip_bfloat16* Hr = (__hip_bfloat16*)(ws + HR_OFF);  // [3][4 ring][640][256] bf16; slot = t&3 holds h(t)
  __hip_bfloat16* Sb = (__hip_bfloat16*)(ws + SB_OFF);  // [3][2 parity][640][768] bf16
  unsigned* sync     = (unsigned*)(ws + SYNC_OFF);

  // ---- XCD-aware role decode: bid%8 == XCD (round-robin dispatch, 24 blocks/XCD).
  //   XCD g (g<6): gate blocks of layer l=g>>1 (48 per layer over 2 XCDs) -- they all
  //   read the same layer-l s-buffer each region, so the re-read is L2-shared.
  //   XCD 6,7: proj blocks (mt split by XCD; the 4 nt sharing an A-tile co-located).
  const int xcd  = bid & 7;
  const int slot = bid >> 3;      // 0..23
  const bool isGate = (xcd < 6);
  int l = 0, hg = 0, mt = 0, nt = 0;
  if (isGate) { l = xcd >> 1; hg = (xcd & 1) * 24 + slot; }      // hg: 0..47 (16 H-cols)
  else        { l = slot >> 3; int r = slot & 7; mt = (xcd - 6) * 2 + (r >> 2); nt = r & 3; }

  const int KX  = (l == 0) ? KX0 : 256;     // x-part K
  const int STW = (l == 0) ? STW1 : STW2;

  const float* Wl  = (l == 0) ? W0  : ((l == 1) ? W1  : W2);
  const float* bl  = (l == 0) ? b0  : ((l == 1) ? b1  : b2);
  const float* Wpl = (l == 0) ? Wp0 : ((l == 1) ? Wp1 : Wp2);

  // ---------- pre-phase: pack x -> Xp (all blocks share the work) ----------
  for (int e = bid * NTHR + tid; e < TT * BB * 64; e += NWG * NTHR) {
    int k  = e & 63;
    int tb = e >> 6;
    float v = (k < DD) ? xin[(size_t)tb * DD + k] : 0.f;
    gst_b16(&Xp[e], __float2bfloat16(v));
  }

  // ---------- pre-phase: pack weights into this block's LDS ----------
  if (isGate) {
    // LDS Wt[nn][kk]: nn = g*16 + hc16 (64 z-cols, ijfo interleaved), kk = K index.
    // kk < KX: x-part from W rows [0:din). kk >= KX: fused Wph = Wp @ Wh (Wh = W rows [din:din+256)).
    const int din = (l == 0) ? DD : 256;
    for (int idx = tid; idx < 64 * KX; idx += NTHR) {
      int kk = idx >> 6;
      int nn = idx & 63;
      int col = (nn >> 4) * HH + hg * 16 + (nn & 15);
      float v = (l == 0) ? ((kk < DD) ? Wl[(size_t)kk * G4H + col] : 0.f)
                         : Wl[(size_t)kk * G4H + col];
      lds[nn * STW + kk] = __float2bfloat16(v);
    }
    // Wph[hrow][nn] = sum_k Wp[hrow][k] * W[din+k][col]; one-time VALU GEMM.
    // Lane layout: nn = lane (coalesced Wl reads), hrow wave-uniform (scalar Wp row).
    for (int idx = tid; idx < 64 * KS; idx += NTHR) {
      int nn   = idx & 63;
      int hrow = idx >> 6;            // 0..767
      int col  = (nn >> 4) * HH + hg * 16 + (nn & 15);
      float a0 = 0.f;
      for (int k = 0; k < PP; ++k)
        a0 += Wpl[(size_t)hrow * PP + k] * Wl[(size_t)(din + k) * G4H + col];
      lds[nn * STW + KX + hrow] = __float2bfloat16(a0);
    }
  } else {
    // LDS Wpt[nn][kk]: nn = local p-col, kk = H row
    for (int idx = tid; idx < 64 * HH; idx += NTHR) {
      int kk = idx >> 6;
      int nn = idx & 63;
      lds[nn * STP + kk] = __float2bfloat16(Wpl[(size_t)kk * PP + nt * 64 + nn]);
    }
  }

  // ---------- per-lane gate setup: 4 waves x 160 rows, block owns 64 z-cols ----------
  const int m0g = wave * 160;
  float biasv[4] = {0.f, 0.f, 0.f, 0.f};
  if (isGate) {
#pragma unroll
    for (int g = 0; g < 4; ++g) biasv[g] = bl[g * HH + hg * 16 + c16];
  }

  f32x4 acc[10][4];    // z-tile accumulator: 10 m-frags x 4 gates (gate g = nfrag g)
  float cst[10][4];    // c-state: 10 m-frags x 4 rows (col = c16)
#pragma unroll
  for (int mi = 0; mi < 10; ++mi) {
#pragma unroll
    for (int g = 0; g < 4; ++g) { acc[mi][g] = f4zero(); cst[mi][g] = 0.f; }
  }

  // gate GEMM: acc += A[m0g:+160, 0:klen] @ Wt[kbase:kbase+klen, :]
  auto gate_gemm = [&](const __hip_bfloat16* A, int lda, int kbase, int klen) {
    for (int ks = 0; ks < klen; ks += 32) {
      s16x8 av[10];
#pragma unroll
      for (int mi = 0; mi < 10; ++mi)
        av[mi] = *(const s16x8*)(A + (size_t)(m0g + mi * 16 + c16) * lda + ks + 8 * q);
      s16x8 bv[4];
#pragma unroll
      for (int g = 0; g < 4; ++g)
        bv[g] = *(const s16x8*)(lds + (g * 16 + c16) * STW + kbase + ks + 8 * q);
#pragma unroll
      for (int mi = 0; mi < 10; ++mi) {
#pragma unroll
        for (int g = 0; g < 4; ++g)
          acc[mi][g] = __builtin_amdgcn_mfma_f32_16x16x32_bf16(av[mi], bv[g], acc[mi][g], 0, 0, 0);
      }
    }
  };

  // c-update + s = sig(o)*tanh(c) -> Sb[l][t&1]; zeroes acc for next region
  auto gate_update = [&](int t) {
    __hip_bfloat16* S = Sb + ((size_t)l * 2 + (t & 1)) * BB * HH;
#pragma unroll
    for (int mi = 0; mi < 10; ++mi) {
#pragma unroll
      for (int r = 0; r < 4; ++r) {
        float iv = acc[mi][0][r] + biasv[0];
        float jv = acc[mi][1][r] + biasv[1];
        float fv = acc[mi][2][r] + biasv[2];
        float ov = acc[mi][3][r] + biasv[3];
        float c  = sigm(fv + 1.f) * cst[mi][r] + sigm(iv) * tanh_(jv);
        cst[mi][r] = c;
        float sv = sigm(ov) * tanh_(c);
        gst_b16(&S[(size_t)(m0g + mi * 16 + q * 4 + r) * HH + hg * 16 + c16],
                __float2bfloat16(sv));
      }
#pragma unroll
      for (int g = 0; g < 4; ++g) acc[mi][g] = f4zero();
    }
  };

  // proj (one step behind gates): h_l(t) = Sb[l][t&1] @ Wp_slice -> Hr slot t&3
  auto proj_do = [&](int t) {
    const __hip_bfloat16* A = Sb + ((size_t)l * 2 + (t & 1)) * BB * HH;
    const int m0p = mt * 160 + (wave >> 1) * 80;
    const int np0 = (wave & 1) * 32;
    f32x4 pa[5][2];
#pragma unroll
    for (int mi = 0; mi < 5; ++mi) { pa[mi][0] = f4zero(); pa[mi][1] = f4zero(); }
    for (int ks = 0; ks < HH; ks += 32) {
      s16x8 av[5];
#pragma unroll
      for (int mi = 0; mi < 5; ++mi)
        av[mi] = *(const s16x8*)(A + (size_t)(m0p + mi * 16 + c16) * HH + ks + 8 * q);
      s16x8 bv[2];
#pragma unroll
      for (int ni = 0; ni < 2; ++ni)
        bv[ni] = *(const s16x8*)(lds + (np0 + ni * 16 + c16) * STP + ks + 8 * q);
#pragma unroll
      for (int mi = 0; mi < 5; ++mi) {
#pragma unroll
        for (int ni = 0; ni < 2; ++ni)
          pa[mi][ni] = __builtin_amdgcn_mfma_f32_16x16x32_bf16(av[mi], bv[ni], pa[mi][ni], 0, 0, 0);
      }
    }
    __hip_bfloat16* Hd = Hr + ((size_t)l * 4 + ((unsigned)t & 3)) * BB * PP;
#pragma unroll
    for (int mi = 0; mi < 5; ++mi)
#pragma unroll
      for (int ni = 0; ni < 2; ++ni)
#pragma unroll
        for (int r = 0; r < 4; ++r)
          gst_b16(&Hd[(size_t)(m0p + mi * 16 + q * 4 + r) * PP + nt * 64 + np0 + ni * 16 + c16],
                  __float2bfloat16(pa[mi][ni][r]));
  };

  // ---------- main scan: ONE grid barrier per region ----------
  // Region s: gates(l) compute t = s-2l:  z(t) = x_l(t)@Wx + s_l(t-1)@Wph, update, write Sb[l][t&1].
  //           proj(l)  compute t = s-2l-1: h_l(t) = Sb[l][t&1] @ Wp -> Hr (next layer's x input).
  // All reads touch only data written in region <= s-1; single barrier per region suffices.
  unsigned bark = 1;
  gridbar(sync, bid, bark++);          // packs done (Xp + LDS weights + Wph)

  for (int s = 0; s < SSTEPS; ++s) {
    if (isGate) {
      const int t = s - 2 * l;
      if (t >= 0 && t < TT) {
        if (l == 0) gate_gemm(Xp + (size_t)t * BB * 64, 64, 0, KX0);
        else        gate_gemm(Hr + ((size_t)(l - 1) * 4 + ((unsigned)t & 3)) * BB * PP, PP, 0, 256);
        gate_gemm(Sb + ((size_t)l * 2 + ((t - 1) & 1)) * BB * HH, HH, KX, KS);
        gate_update(t);
      }
    } else {
      const int tp = s - 2 * l - 1;
      if (tp >= 0 && tp < TT) proj_do(tp);
    }
    gridbar(sync, bid, bark++);
  }

  // ---------- epilogue: L2-normalize h_2(159) (ring slot 159&3 = 3) ----------
  const __hip_bfloat16* hf = Hr + (size_t)(2 * 4 + 3) * BB * PP;
  float* red = reinterpret_cast<float*>(lds);   // weights dead now, reuse LDS
  for (int row = bid; row < BB; row += NWG) {
    float v = __bfloat162float(hf[(size_t)row * PP + tid]);
    float ssq = v * v;
#pragma unroll
    for (int off = 32; off > 0; off >>= 1) ssq += __shfl_down(ssq, off, 64);
    if (lane == 0) red[wave] = ssq;
    __syncthreads();
    float tot = red[0] + red[1] + red[2] + red[3];
    outp[(size_t)row * PP + tid] = v * __fdividef(1.f, sqrtf(tot) + 1e-6f);
    __syncthreads();
  }
}

extern "C" void kernel_launch(void* const* d_in, const int* in_sizes, int n_in,
                              void* d_out, int out_size, void* d_ws, size_t ws_size,
                              hipStream_t stream) {
  (void)in_sizes; (void)n_in; (void)out_size; (void)ws_size;
  unsigned char* ws = (unsigned char*)d_ws;
  // zero s-buffers (s(-1) = 0), h-ring, and barrier counters every call (replay-safe)
  hipMemsetAsync(ws + HR_OFF, 0, HR_BYTES, stream);
  hipMemsetAsync(ws + SB_OFF, 0, SB_BYTES, stream);
  hipMemsetAsync(ws + SYNC_OFF, 0, SYNC_BYTES, stream);
  lstmp_persistent<<<dim3(NWG), dim3(NTHR), 0, stream>>>(
      (const float*)d_in[0],
      (const float*)d_in[1], (const float*)d_in[2], (const float*)d_in[3],
      (const float*)d_in[4], (const float*)d_in[5], (const float*)d_in[6],
      (const float*)d_in[7], (const float*)d_in[8], (const float*)d_in[9],
      (float*)d_out, ws);
}

// Round 3
// 7467.666 us; speedup vs baseline: 1.9330x; 1.9330x over previous
//
#include <hip/hip_runtime.h>
#include <hip/hip_bf16.h>

typedef __attribute__((ext_vector_type(4))) float f32x4;
typedef __attribute__((ext_vector_type(8))) short s16x8;

#define DEVFN static __device__ __forceinline__

// ---- problem sizes ----
#define TT  160
#define BB  640
#define DD  40
#define HH  768
#define PP  256
#define G4H 3072

// ---- geometry (round-0 proven config) ----
#define NGATE 144      // 3 layers * 2 bc * 24 hg
#define NPROJ 48       // 3 layers * 4 mt * 4 nt
#define NWG   192
#define NTHR  256
#define SSTEPS 164     // 160 + 2*2 pipeline skew

#define KH  256
#define KX0 64         // layer0 x-K padded 40 -> 64

// LDS strides (elements), +8 pad keeps 16B alignment and breaks worst conflicts
#define STW1 328       // layer0: 320+8
#define STW2 520       // layer1/2: 512+8
#define STP  776       // proj: 768+8
#define LDS_ELEMS 66560  // 128*520 = 133,120 bytes

// ---- workspace layout ----
#define XP_BYTES   (TT*BB*64*2)
#define HR_BYTES   (3*4*BB*PP*2)
#define SB_BYTES   (3*BB*HH*2)
#define XP_OFF     0
#define HR_OFF     (XP_OFF + XP_BYTES)
#define SB_OFF     (HR_OFF + HR_BYTES)
#define SYNC_OFF   (SB_OFF + SB_BYTES)
#define SYNC_BYTES 4096

DEVFN float sigm(float v)  { return __fdividef(1.f, 1.f + __expf(-v)); }
DEVFN float tanh_(float v) { return 2.f * __fdividef(1.f, 1.f + __expf(-2.f * v)) - 1.f; }
DEVFN f32x4 f4zero() { f32x4 v; v[0]=0.f; v[1]=0.f; v[2]=0.f; v[3]=0.f; return v; }

// write-through bf16 store: visible at coherence point once vmcnt retires,
// no L2 writeback fence needed on the release side.
DEVFN void gst_b16(__hip_bfloat16* p, __hip_bfloat16 v) {
  unsigned short u = __builtin_bit_cast(unsigned short, v);
  asm volatile("global_store_short %0, %1, off sc0 sc1" :: "v"(p), "v"(u));
}

// cache-bypassing 4B load/store (coherence-point access, fresh values)
DEVFN unsigned ld_cc(const unsigned* p) {
  unsigned v;
  asm volatile("global_load_dword %0, %1, off sc0 sc1\n\ts_waitcnt vmcnt(0)"
               : "=v"(v) : "v"(p) : "memory");
  return v;
}
DEVFN void st_cc(unsigned* p, unsigned v) {
  asm volatile("global_store_dword %0, %1, off sc0 sc1" :: "v"(p), "v"(v) : "memory");
}
DEVFN void ld3_cc(const unsigned* p0, const unsigned* p1, const unsigned* p2,
                  unsigned& a, unsigned& b, unsigned& c) {
  asm volatile("global_load_dword %0, %3, off sc0 sc1\n\t"
               "global_load_dword %1, %4, off sc0 sc1\n\t"
               "global_load_dword %2, %5, off sc0 sc1\n\t"
               "s_waitcnt vmcnt(0)"
               : "=&v"(a), "=&v"(b), "=&v"(c)
               : "v"(p0), "v"(p1), "v"(p2) : "memory");
}

// ---- flag-array grid barrier: ZERO atomic contention.
// sync[0] = epoch; sync[64+i] = arrival flag of block i (plain write-through
// stores to distinct addresses -- 192 parallel stores, no serialization).
// Master = block 0 wave 0: polls all 192 flags with 3 batched bypass-loads,
// publishes epoch. Everyone spins on the single epoch word.
// k = 1,2,3,... strictly increasing.
DEVFN void gridbar(unsigned* sync, int bid, int tid, unsigned k) {
  __syncthreads();   // compiler drains vmcnt(0): all sc0sc1 stores at coherence point
  if (tid == 0) st_cc(sync + 64 + bid, k);
  if (bid == 0 && tid < 64) {
    unsigned a, b, c;
    for (;;) {
      ld3_cc(sync + 64 + tid, sync + 128 + tid, sync + 192 + tid, a, b, c);
      if (__all((a >= k) & (b >= k) & (c >= k))) break;
      __builtin_amdgcn_s_sleep(1);
    }
    if (tid == 0) st_cc(sync, k);
  }
  if (tid == 0) {
    while (ld_cc(sync) < k) __builtin_amdgcn_s_sleep(1);
    __builtin_amdgcn_fence(__ATOMIC_ACQUIRE, "agent");  // buffer_inv: kill stale L1/L2 lines
  }
  __syncthreads();
}

__global__ __launch_bounds__(NTHR, 1)
void lstmp_persistent(const float* __restrict__ xin,
                      const float* __restrict__ W0, const float* __restrict__ b0, const float* __restrict__ Wp0,
                      const float* __restrict__ W1, const float* __restrict__ b1, const float* __restrict__ Wp1,
                      const float* __restrict__ W2, const float* __restrict__ b2, const float* __restrict__ Wp2,
                      float* __restrict__ outp, unsigned char* __restrict__ ws)
{
  __shared__ __align__(16) __hip_bfloat16 lds[LDS_ELEMS];

  const int bid  = blockIdx.x;
  const int tid  = threadIdx.x;
  const int lane = tid & 63;
  const int wave = tid >> 6;
  const int q    = lane >> 4;     // 0..3
  const int c16  = lane & 15;

  __hip_bfloat16* Xp = (__hip_bfloat16*)(ws + XP_OFF);  // [160][640][64] bf16, cols>=40 zero
  __hip_bfloat16* Hr = (__hip_bfloat16*)(ws + HR_OFF);  // [3][4 ring][640][256] bf16
  __hip_bfloat16* Sb = (__hip_bfloat16*)(ws + SB_OFF);  // [3][640][768] bf16
  unsigned* sync     = (unsigned*)(ws + SYNC_OFF);

  // ---- XCD-aware role decode: bid%8 == XCD (round-robin dispatch, 24 blocks/XCD).
  // All readers of the same communicated tile share one XCD's L2:
  //   XCD g (g<6): gate group (l=g>>1, bc=g&1) -- 24 hg blocks share one h-tile.
  //   XCD 6: proj mt {0,1}; XCD 7: proj mt {2,3} (nt sharing an A-tile co-located).
  const int xcd  = bid & 7;
  const int slot = bid >> 3;      // 0..23
  const bool isGate = (xcd < 6);
  int l = 0, bc = 0, hg = 0, mt = 0, nt = 0;
  if (isGate) { l = xcd >> 1; bc = xcd & 1; hg = slot; }
  else        { l = slot >> 3; int r = slot & 7; mt = (xcd - 6) * 2 + (r >> 2); nt = r & 3; }

  const int KX  = (l == 0) ? KX0 : 256;
  const int KT  = KX + KH;                  // 320 or 512
  const int STW = (l == 0) ? STW1 : STW2;

  const float* Wl  = (l == 0) ? W0  : ((l == 1) ? W1  : W2);
  const float* bl  = (l == 0) ? b0  : ((l == 1) ? b1  : b2);
  const float* Wpl = (l == 0) ? Wp0 : ((l == 1) ? Wp1 : Wp2);

  // ---------- pre-phase: pack x -> Xp (all blocks share the work) ----------
  for (int e = bid * NTHR + tid; e < TT * BB * 64; e += NWG * NTHR) {
    int k  = e & 63;
    int tb = e >> 6;
    float v = (k < DD) ? xin[(size_t)tb * DD + k] : 0.f;
    gst_b16(&Xp[e], __float2bfloat16(v));
  }

  // ---------- pre-phase: pack weights (transposed) into this block's LDS ----------
  if (isGate) {
    // LDS Wt[nn][kk]: nn = g*32 + hcw  (gate-major), kk = K index (x rows then h rows)
    for (int idx = tid; idx < 128 * KT; idx += NTHR) {
      int kk = idx >> 7;
      int nn = idx & 127;
      int col = (nn >> 5) * HH + hg * 32 + (nn & 31);
      float v;
      if (l == 0) {
        v = (kk < DD) ? Wl[(size_t)kk * G4H + col]
                      : ((kk < KX0) ? 0.f : Wl[(size_t)(kk - 24) * G4H + col]);
      } else {
        v = Wl[(size_t)kk * G4H + col];
      }
      lds[nn * STW + kk] = __float2bfloat16(v);
    }
  } else {
    // LDS Wpt[nn][kk]: nn = local p-col, kk = H row
    for (int idx = tid; idx < 64 * HH; idx += NTHR) {
      int kk = idx >> 6;
      int nn = idx & 63;
      lds[nn * STP + kk] = __float2bfloat16(Wpl[(size_t)kk * PP + nt * 64 + nn]);
    }
  }

  // ---------- per-lane gate setup ----------
  const int wmg = wave >> 1, wng = wave & 1;
  const int m0g = bc * 320 + wmg * 160;      // this wave's batch-row base (gate)
  const int hcl = wng * 16 + c16;            // 0..31 within WG's 32 h-cols
  float biasv[4] = {0.f, 0.f, 0.f, 0.f};
  if (isGate) {
#pragma unroll
    for (int g = 0; g < 4; ++g) biasv[g] = bl[g * HH + hg * 32 + hcl];
  }

  f32x4 acc[10][4];    // z-tile accumulator: 10 m-frags x 4 gates
  float cst[10][4];    // c-state: 10 m-frags x 4 rows
#pragma unroll
  for (int mi = 0; mi < 10; ++mi) {
#pragma unroll
    for (int g = 0; g < 4; ++g) { acc[mi][g] = f4zero(); cst[mi][g] = 0.f; }
  }

  // gate GEMM: acc += A[m0g:+160, 0:klen] @ Wt[kbase:kbase+klen, :]
  auto gate_gemm = [&](const __hip_bfloat16* A, int lda, int kbase, int klen) {
    for (int ks = 0; ks < klen; ks += 32) {
      s16x8 av[10];
#pragma unroll
      for (int mi = 0; mi < 10; ++mi)
        av[mi] = *(const s16x8*)(A + (size_t)(m0g + mi * 16 + c16) * lda + ks + 8 * q);
      s16x8 bv[4];
#pragma unroll
      for (int g = 0; g < 4; ++g)
        bv[g] = *(const s16x8*)(lds + (g * 32 + hcl) * STW + kbase + ks + 8 * q);
#pragma unroll
      for (int mi = 0; mi < 10; ++mi) {
#pragma unroll
        for (int g = 0; g < 4; ++g)
          acc[mi][g] = __builtin_amdgcn_mfma_f32_16x16x32_bf16(av[mi], bv[g], acc[mi][g], 0, 0, 0);
      }
    }
  };

  // c-update + s = sig(o)*tanh(c) -> Sbuf; zeroes acc for the next x-shadow
  auto gate_update = [&]() {
    __hip_bfloat16* S = Sb + (size_t)l * BB * HH;
#pragma unroll
    for (int mi = 0; mi < 10; ++mi) {
#pragma unroll
      for (int r = 0; r < 4; ++r) {
        float iv = acc[mi][0][r] + biasv[0];
        float jv = acc[mi][1][r] + biasv[1];
        float fv = acc[mi][2][r] + biasv[2];
        float ov = acc[mi][3][r] + biasv[3];
        float c  = sigm(fv + 1.f) * cst[mi][r] + sigm(iv) * tanh_(jv);
        cst[mi][r] = c;
        float sv = sigm(ov) * tanh_(c);
        gst_b16(&S[(size_t)(m0g + mi * 16 + q * 4 + r) * HH + hg * 32 + hcl],
                __float2bfloat16(sv));
      }
#pragma unroll
      for (int g = 0; g < 4; ++g) acc[mi][g] = f4zero();
    }
  };

  // proj: h_t[tile] = Sb[l] @ Wp_slice -> Hr ring slot (t+1)&3
  auto proj_do = [&](int t) {
    const __hip_bfloat16* A = Sb + (size_t)l * BB * HH;
    const int m0p = mt * 160 + (wave >> 1) * 80;
    const int np0 = (wave & 1) * 32;
    f32x4 pa[5][2];
#pragma unroll
    for (int mi = 0; mi < 5; ++mi) { pa[mi][0] = f4zero(); pa[mi][1] = f4zero(); }
    for (int ks = 0; ks < HH; ks += 32) {
      s16x8 av[5];
#pragma unroll
      for (int mi = 0; mi < 5; ++mi)
        av[mi] = *(const s16x8*)(A + (size_t)(m0p + mi * 16 + c16) * HH + ks + 8 * q);
      s16x8 bv[2];
#pragma unroll
      for (int ni = 0; ni < 2; ++ni)
        bv[ni] = *(const s16x8*)(lds + (np0 + ni * 16 + c16) * STP + ks + 8 * q);
#pragma unroll
      for (int mi = 0; mi < 5; ++mi) {
#pragma unroll
        for (int ni = 0; ni < 2; ++ni)
          pa[mi][ni] = __builtin_amdgcn_mfma_f32_16x16x32_bf16(av[mi], bv[ni], pa[mi][ni], 0, 0, 0);
      }
    }
    __hip_bfloat16* Hd = Hr + ((size_t)l * 4 + ((unsigned)(t + 1) & 3)) * BB * PP;
#pragma unroll
    for (int mi = 0; mi < 5; ++mi)
#pragma unroll
      for (int ni = 0; ni < 2; ++ni)
#pragma unroll
        for (int r = 0; r < 4; ++r)
          gst_b16(&Hd[(size_t)(m0p + mi * 16 + q * 4 + r) * PP + nt * 64 + np0 + ni * 16 + c16],
                  __float2bfloat16(pa[mi][ni][r]));
  };

  // ---------- main pipelined scan ----------
  unsigned bark = 1;
  gridbar(sync, bid, tid, bark++);          // packs done (Xp + LDS)

  if (isGate && l == 0) gate_gemm(Xp, 64, 0, KX0);   // zx(0) for layer 0

  for (int s = 0; s < SSTEPS; ++s) {
    const int t = s - 2 * l;           // this layer's timestep
    // phase 1: gates (acc already holds zx(t)) + c-update + s-write
    if (isGate && t >= 0 && t < TT) {
      gate_gemm(Hr + ((size_t)l * 4 + ((unsigned)t & 3)) * BB * PP, PP, KX, KH);  // h_{t-1} part
      gate_update();
    }
    gridbar(sync, bid, tid, bark++);
    // phase 2: proj(t)  ||  gate x-shadow: zx(t+1)
    if (isGate) {
      const int tp = t + 1;
      if (tp >= 0 && tp < TT) {
        if (l == 0) gate_gemm(Xp + (size_t)tp * BB * 64, 64, 0, KX0);
        else        gate_gemm(Hr + ((size_t)(l - 1) * 4 + ((unsigned)(tp + 1) & 3)) * BB * PP, PP, 0, 256);
      }
    } else if (t >= 0 && t < TT) {
      proj_do(t);
    }
    gridbar(sync, bid, tid, bark++);
  }

  // ---------- epilogue: L2-normalize h^2[159] (ring slot 0) ----------
  const __hip_bfloat16* hf = Hr + (size_t)(2 * 4 + 0) * BB * PP;
  float* red = reinterpret_cast<float*>(lds);   // weights dead now, reuse LDS
  for (int row = bid; row < BB; row += NWG) {
    float v = __bfloat162float(hf[(size_t)row * PP + tid]);
    float ssq = v * v;
#pragma unroll
    for (int off = 32; off > 0; off >>= 1) ssq += __shfl_down(ssq, off, 64);
    if (lane == 0) red[wave] = ssq;
    __syncthreads();
    float tot = red[0] + red[1] + red[2] + red[3];
    outp[(size_t)row * PP + tid] = v * __fdividef(1.f, sqrtf(tot) + 1e-6f);
    __syncthreads();
  }
}

extern "C" void kernel_launch(void* const* d_in, const int* in_sizes, int n_in,
                              void* d_out, int out_size, void* d_ws, size_t ws_size,
                              hipStream_t stream) {
  (void)in_sizes; (void)n_in; (void)out_size; (void)ws_size;
  unsigned char* ws = (unsigned char*)d_ws;
  // zero h-ring (h_{-1} = 0) and barrier flags every call (replay-safe)
  hipMemsetAsync(ws + HR_OFF, 0, HR_BYTES, stream);
  hipMemsetAsync(ws + SYNC_OFF, 0, SYNC_BYTES, stream);
  lstmp_persistent<<<dim3(NWG), dim3(NTHR), 0, stream>>>(
      (const float*)d_in[0],
      (const float*)d_in[1], (const float*)d_in[2], (const float*)d_in[3],
      (const float*)d_in[4], (const float*)d_in[5], (const float*)d_in[6],
      (const float*)d_in[7], (const float*)d_in[8], (const float*)d_in[9],
      (float*)d_out, ws);
}